// Round 5
// baseline (134.964 us; speedup 1.0000x reference)
//
#include <hip/hip_runtime.h>

typedef __attribute__((ext_vector_type(8))) short short8v;
typedef __attribute__((ext_vector_type(4))) float f32x4;

#define NN 8192
#define HDIM 64
#define KDIM 128
#define LOG2E 1.44269504088896340736f

__device__ __forceinline__ unsigned short f2b(float f) {
    unsigned int u = __float_as_uint(f);
    return (unsigned short)((u + 0x7fffu + ((u >> 16) & 1u)) >> 16);
}
__device__ __forceinline__ float b2f(unsigned short s) {
    return __uint_as_float(((unsigned int)s) << 16);
}

// ---------------- Kernel 1 (verified R3/R4): H = X@W, softmax row constants, HbT bf16 ----
__global__ __launch_bounds__(256) void gat_prep(
    const float* __restrict__ X, const float* __restrict__ W,
    const float* __restrict__ al, const float* __restrict__ ar,
    unsigned short* __restrict__ HbT, float* __restrict__ el2p,
    float* __restrict__ cpv, float* __restrict__ erp)
{
    __shared__ float Wl[KDIM * HDIM];
    const int t = threadIdx.x;
    {
        const float4* Wv = (const float4*)W;
        float4* Wlv = (float4*)Wl;
#pragma unroll
        for (int s = 0; s < 8; ++s) Wlv[t + s * 256] = Wv[t + s * 256];
    }
    __syncthreads();
    const int row = blockIdx.x * 32 + (t >> 3);
    const int cg = t & 7;
    const int c0 = cg * 8;
    float al8[8], ar8[8];
#pragma unroll
    for (int j = 0; j < 8; ++j) { al8[j] = al[c0 + j]; ar8[j] = ar[c0 + j]; }
    float acc[8];
#pragma unroll
    for (int j = 0; j < 8; ++j) acc[j] = 0.f;
    const float4* Xv = (const float4*)(X + row * KDIM);
    for (int k4 = 0; k4 < 32; ++k4) {
        float4 x4 = Xv[k4];
        float xs[4] = {x4.x, x4.y, x4.z, x4.w};
#pragma unroll
        for (int kk = 0; kk < 4; ++kk) {
            const int k = k4 * 4 + kk;
            const float x = xs[kk];
            const float4 w0 = *(const float4*)&Wl[k * HDIM + c0];
            const float4 w1 = *(const float4*)&Wl[k * HDIM + c0 + 4];
            acc[0] = fmaf(x, w0.x, acc[0]); acc[1] = fmaf(x, w0.y, acc[1]);
            acc[2] = fmaf(x, w0.z, acc[2]); acc[3] = fmaf(x, w0.w, acc[3]);
            acc[4] = fmaf(x, w1.x, acc[4]); acc[5] = fmaf(x, w1.y, acc[5]);
            acc[6] = fmaf(x, w1.z, acc[6]); acc[7] = fmaf(x, w1.w, acc[7]);
        }
    }
    float pl = 0.f, pr = 0.f;
#pragma unroll
    for (int j = 0; j < 8; ++j) {
        pl = fmaf(acc[j], al8[j], pl);
        pr = fmaf(acc[j], ar8[j], pr);
    }
    pl += __shfl_xor(pl, 1, 64); pl += __shfl_xor(pl, 2, 64); pl += __shfl_xor(pl, 4, 64);
    pr += __shfl_xor(pr, 1, 64); pr += __shfl_xor(pr, 2, 64); pr += __shfl_xor(pr, 4, 64);
    if (cg == 0) {
        const float el = pl;
        // m_i = leaky(e_l + 8): row upper bound; softmax shift-invariance makes it EXACT.
        const float s8 = el + 8.0f;
        const float m = fmaxf(s8, 0.2f * s8);
        el2p[row] = (el - m) * LOG2E;
        cpv[row] = -0.8f * m * LOG2E;
        erp[row] = pr * LOG2E;
    }
#pragma unroll
    for (int j = 0; j < 8; ++j) HbT[(c0 + j) * NN + row] = f2b(acc[j]);
}

// ---------------- Kernel 2: wave-independent scatter. No LDS, no barriers. ----------
// 2048 waves: wave owns 16 rows x 2048 cols. Swapped MFMA C^T = H^T . p^T makes the
// p-fragment lane-local (lane l computes p[row=l&15][cols (l>>4)*8+e mod 32]).
__global__ __launch_bounds__(256) void gat_scatter(
    const int* __restrict__ A, const unsigned short* __restrict__ HbT,
    const float* __restrict__ el2p, const float* __restrict__ cpv,
    const float* __restrict__ erp, float* __restrict__ out, float* __restrict__ dsum)
{
    const int t = threadIdx.x;
    const int l = t & 63;
    const int wid = blockIdx.x * 4 + (t >> 6);   // 0..2047
    const int rowbase = (wid >> 2) * 16;
    const long jqb = (long)(wid & 3) * 2048;
    const int l15 = l & 15, lq = l >> 4;
    const int row = rowbase + l15;
    const float el2c = el2p[row], cpc = cpv[row];
    const int* Arow = A + (long)row * NN + jqb + lq * 8;
    const float* erb = erp + jqb + lq * 8;
    const unsigned short* Hb = HbT + (long)l15 * NN + jqb + lq * 8;

    f32x4 acc0 = {0,0,0,0}, acc1 = {0,0,0,0}, acc2 = {0,0,0,0}, acc3 = {0,0,0,0};
    float rs = 0.f;
    int4 bufA[16], bufB[16]; // 256-col group = 8 chunks x 2 int4 per lane

    auto loadG = [&](int4* buf, int g) {
        const int4* p = (const int4*)(Arow + (long)g * 256);
#pragma unroll
        for (int kc = 0; kc < 8; ++kc) {
            buf[2 * kc] = p[kc * 8];
            buf[2 * kc + 1] = p[kc * 8 + 1];
        }
    };

    auto doG = [&](const int4* buf, int g) {
#pragma unroll
        for (int kc = 0; kc < 8; ++kc) {
            const int cb = g * 256 + kc * 32;
            const float4 e0 = *(const float4*)(erb + cb);
            const float4 e1 = *(const float4*)(erb + cb + 4);
            const int am[8] = {buf[2*kc].x, buf[2*kc].y, buf[2*kc].z, buf[2*kc].w,
                               buf[2*kc+1].x, buf[2*kc+1].y, buf[2*kc+1].z, buf[2*kc+1].w};
            const float ev[8] = {e0.x, e0.y, e0.z, e0.w, e1.x, e1.y, e1.z, e1.w};
            union { unsigned int u[4]; short8v v; } pu;
#pragma unroll
            for (int h = 0; h < 4; ++h) {
                float u0 = el2c + ev[2 * h];
                float v0 = fmaf(u0, 0.2f, cpc);
                float g0 = fmaxf(u0, v0);
                g0 = am[2 * h] ? g0 : -1e30f;
                const unsigned short b0 = f2b(exp2f(g0));
                float u1 = el2c + ev[2 * h + 1];
                float v1 = fmaf(u1, 0.2f, cpc);
                float g1 = fmaxf(u1, v1);
                g1 = am[2 * h + 1] ? g1 : -1e30f;
                const unsigned short b1 = f2b(exp2f(g1));
                rs += b2f(b0) + b2f(b1); // denominator from ROUNDED p (matches numerator)
                pu.u[h] = (unsigned int)b0 | ((unsigned int)b1 << 16);
            }
            const unsigned short* hp = Hb + cb;
            const short8v h0 = *(const short8v*)(hp);
            const short8v h1 = *(const short8v*)(hp + 16 * NN);
            const short8v h2 = *(const short8v*)(hp + 32 * NN);
            const short8v h3 = *(const short8v*)(hp + 48 * NN);
            acc0 = __builtin_amdgcn_mfma_f32_16x16x32_bf16(h0, pu.v, acc0, 0, 0, 0);
            acc1 = __builtin_amdgcn_mfma_f32_16x16x32_bf16(h1, pu.v, acc1, 0, 0, 0);
            acc2 = __builtin_amdgcn_mfma_f32_16x16x32_bf16(h2, pu.v, acc2, 0, 0, 0);
            acc3 = __builtin_amdgcn_mfma_f32_16x16x32_bf16(h3, pu.v, acc3, 0, 0, 0);
        }
    };

    // straight-line 2-group-deep register pipeline (8 groups of 256 cols)
    loadG(bufA, 0);
    loadG(bufB, 1);
    doG(bufA, 0);
    loadG(bufA, 2);
    doG(bufB, 1);
    loadG(bufB, 3);
    doG(bufA, 2);
    loadG(bufA, 4);
    doG(bufB, 3);
    loadG(bufB, 5);
    doG(bufA, 4);
    loadG(bufA, 6);
    doG(bufB, 5);
    loadG(bufB, 7);
    doG(bufA, 6);
    doG(bufB, 7);

    // denominator partial: 4 lanes (lq groups) share row l15
    rs += __shfl_xor(rs, 16, 64);
    rs += __shfl_xor(rs, 32, 64);
    if (l < 16) atomicAdd(dsum + row, rs);

    // numerator partial: acc[nt][r] = (p.H)[row=l15][col=nt*16+lq*4+r]
    float* ob = out + (long)row * HDIM + lq * 4;
#pragma unroll
    for (int r = 0; r < 4; ++r) {
        atomicAdd(ob + 0 + r, acc0[r]);
        atomicAdd(ob + 16 + r, acc1[r]);
        atomicAdd(ob + 32 + r, acc2[r]);
        atomicAdd(ob + 48 + r, acc3[r]);
    }
}

// ---------------- Kernel 3: out *= 1/dsum[row] ------------------------------------
__global__ __launch_bounds__(256) void gat_norm(float* __restrict__ out,
                                                const float* __restrict__ dsum)
{
    const int i4 = blockIdx.x * 256 + threadIdx.x; // float4 index; 16 per row
    float4 v = ((float4*)out)[i4];
    const float ri = 1.0f / dsum[i4 >> 4];
    v.x *= ri; v.y *= ri; v.z *= ri; v.w *= ri;
    ((float4*)out)[i4] = v;
}

extern "C" void kernel_launch(void* const* d_in, const int* in_sizes, int n_in,
                              void* d_out, int out_size, void* d_ws, size_t ws_size,
                              hipStream_t stream) {
    const float *X = nullptr, *W = nullptr, *al = nullptr, *ar = nullptr;
    const int* A = nullptr;
    for (int i = 0; i < n_in; ++i) {
        const long s = in_sizes[i];
        if (s == (long)NN * NN) A = (const int*)d_in[i];
        else if (s == (long)NN * KDIM) X = (const float*)d_in[i];
        else if (s == (long)KDIM * HDIM) W = (const float*)d_in[i];
        else if (s == HDIM) { if (!al) al = (const float*)d_in[i]; else ar = (const float*)d_in[i]; }
    }
    float* out = (float*)d_out;
    // ws: HbT (1MB) + el2p/cpv/erp/dsum (4 x 32KB)
    unsigned short* HbT = (unsigned short*)d_ws;
    float* el2p = (float*)((char*)d_ws + (long)NN * HDIM * 2);
    float* cpv = el2p + NN;
    float* erp = cpv + NN;
    float* dsum = erp + NN;
    hipMemsetAsync(d_out, 0, (long)NN * HDIM * sizeof(float), stream);
    hipMemsetAsync(dsum, 0, NN * sizeof(float), stream);
    hipLaunchKernelGGL(gat_prep, dim3(256), dim3(256), 0, stream, X, W, al, ar, HbT, el2p, cpv, erp);
    hipLaunchKernelGGL(gat_scatter, dim3(512), dim3(256), 0, stream, A, HbT, el2p, cpv, erp, out, dsum);
    hipLaunchKernelGGL(gat_norm, dim3(512), dim3(256), 0, stream, out, dsum);
}